// Round 12
// baseline (1094.608 us; speedup 1.0000x reference)
//
#include <hip/hip_runtime.h>
#include <stdint.h>

#define TT 512

typedef __fp16   f16x8  __attribute__((ext_vector_type(8)));
typedef float    f32x4  __attribute__((ext_vector_type(4)));
typedef __fp16   fp16x2 __attribute__((ext_vector_type(2)));
typedef uint32_t u32x2  __attribute__((ext_vector_type(2)));

__device__ __forceinline__ f32x4 mfma16(f16x8 a, f16x8 b, f32x4 c) {
    return __builtin_amdgcn_mfma_f32_16x16x32_f16(a, b, c, 0, 0, 0);
}
__device__ __forceinline__ uint32_t pkf16(float a, float b) {
    fp16x2 h = __builtin_amdgcn_cvt_pkrtz(a, b);
    return __builtin_bit_cast(uint32_t, h);
}

#define REP4(M) M(0)M(1)M(2)M(3)

// A-operand gather with per-column scale SC (weights transposed, z^T form):
// A[m=16T+l15][k=32F+8q+j] = SRC[k][16T+l15] * SC
#define GA(SRC, T, F, SC) (f16x8){ \
  (__fp16)((SRC)[(32*(F)+8*quad+0)*256 + 16*(T)+l15] * (SC)), \
  (__fp16)((SRC)[(32*(F)+8*quad+1)*256 + 16*(T)+l15] * (SC)), \
  (__fp16)((SRC)[(32*(F)+8*quad+2)*256 + 16*(T)+l15] * (SC)), \
  (__fp16)((SRC)[(32*(F)+8*quad+3)*256 + 16*(T)+l15] * (SC)), \
  (__fp16)((SRC)[(32*(F)+8*quad+4)*256 + 16*(T)+l15] * (SC)), \
  (__fp16)((SRC)[(32*(F)+8*quad+5)*256 + 16*(T)+l15] * (SC)), \
  (__fp16)((SRC)[(32*(F)+8*quad+6)*256 + 16*(T)+l15] * (SC)), \
  (__fp16)((SRC)[(32*(F)+8*quad+7)*256 + 16*(T)+l15] * (SC)) }

// Wave (l,w) owns tiles Tg = 4*j + w (j = gate: 0:i 1:f 2:g 3:o), i.e.
// z-cols 64j+16w..+15 -> units 16w..16w+15, all 4 gates. 8 W + 8 U MFMA/step.
// i/f/o columns pre-scaled by -log2e (R19 fold); bias pre-scaled in LDS table.
#define DECLT(j) f16x8 uA##j##_0, uA##j##_1, wA##j##_0, wA##j##_1;
#define LOADT(j) { \
  const int Tg_ = 4*(j) + w; \
  const float sc_ = ((j) == 2) ? 1.0f : -1.4426950408889634f; \
  uA##j##_0 = GA(Uw, Tg_, 0, sc_); uA##j##_1 = GA(Uw, Tg_, 1, sc_); \
  if (l > 0) { wA##j##_0 = GA(Wsrc, Tg_, 0, sc_); wA##j##_1 = GA(Wsrc, Tg_, 1, sc_); } \
  else { wA##j##_0 = __builtin_bit_cast(f16x8, (f32x4){ \
           Wx0[16*Tg_+4*quad+0] * sc_, Wx0[16*Tg_+4*quad+1] * sc_, \
           Wx0[16*Tg_+4*quad+2] * sc_, Wx0[16*Tg_+4*quad+3] * sc_ }); \
         wA##j##_1 = wA##j##_0; } }

#define MW0(j) acc##j = mfma16(wA##j##_0, xBp0, bias##j);
#define MW1(j) acc##j = mfma16(wA##j##_1, xBp1, acc##j);
#define MX(j)  acc##j = bias##j + __builtin_bit_cast(f32x4, wA##j##_0) * xvp4;
#define MU0(j) acc##j = mfma16(uA##j##_0, hB0, acc##j);
#define MU1(j) acc##j = mfma16(uA##j##_1, hB1, acc##j);

// MFMA segment (R14 proven order): bias + hB ds_reads at top, latency hides
// under the partner-independent W burst; U burst last.
#define MFMA_SEG(t_) { \
  f32x4 bias0 = *(const f32x4*)(bsl +   0); \
  f32x4 bias1 = *(const f32x4*)(bsl +  64); \
  f32x4 bias2 = *(const f32x4*)(bsl + 128); \
  f32x4 bias3 = *(const f32x4*)(bsl + 192); \
  const __fp16* hp_ = hb_l + (((t_)-1)&7)*1152 + l15*72 + 8*quad; \
  f16x8 hB0 = *(const f16x8*)hp_; \
  f16x8 hB1 = *(const f16x8*)(hp_ + 32); \
  if (l > 0) { REP4(MW0) REP4(MW1) } \
  else       { f32x4 xvp4 = {xvp, xvp, xvp, xvp}; REP4(MX) } \
  REP4(MU0) \
  REP4(MU1) }

// Gates: z' for i/f/o pre-scaled -> exp2 direct; g unscaled (relu only).
#define GATE_SEG(tg_, SV_) { \
  f32x4 ei_, ef_, eo_; \
  _Pragma("unroll") for (int r_ = 0; r_ < 4; ++r_) { \
    ei_[r_] = __builtin_amdgcn_exp2f(acc0[r_]); \
    ef_[r_] = __builtin_amdgcn_exp2f(acc1[r_]); \
    eo_[r_] = __builtin_amdgcn_exp2f(acc3[r_]); \
  } \
  f32x4 si_, sf_, so_; \
  _Pragma("unroll") for (int r_ = 0; r_ < 4; ++r_) { \
    si_[r_] = __builtin_amdgcn_rcpf(1.0f + ei_[r_]); \
    sf_[r_] = __builtin_amdgcn_rcpf(1.0f + ef_[r_]); \
    so_[r_] = __builtin_amdgcn_rcpf(1.0f + eo_[r_]); \
  } \
  const f32x4 z4_ = {0.f, 0.f, 0.f, 0.f}; \
  f32x4 rg_ = __builtin_elementwise_max(acc2, z4_); \
  f32x4 cv_ = sf_ * cst0 + si_ * rg_; \
  cst0 = cv_; \
  f32x4 hv_ = so_ * __builtin_elementwise_max(cv_, z4_); \
  u32x2 pv_ = { pkf16(hv_[0], hv_[1]), pkf16(hv_[2], hv_[3]) }; \
  __fp16* hw_ = hb_l + ((tg_)&7)*1152 + l15*72 + 16*w + 4*quad; \
  *(u32x2*)hw_ = pv_; \
  if (SV_) hK0 = hv_; }

#define PLOAD(idx) __hip_atomic_load(&Pw[idx], __ATOMIC_ACQUIRE, __HIP_MEMORY_SCOPE_WORKGROUP)

// 64 blocks x 1024 threads; block = 16 batch rows; 16 waves = 4 layers x 4
// unit-quarters; 4 waves/SIMD (TLP test, take 2). R21's result was VOID: its
// fetch_add flag publish advanced counters by 64/step (per-lane atomics!) ->
// protocol dead -> races (absmax 468 / 2.9e-6). R22 fixes:
//  (1) publish = wave-idempotent atomic_store(t+1) (R14-R20 semantics)
//  (2) epilogue BIT-EXACT to R14: hK0 frags staged to LDS, waves (3,0/1)
//      reassemble R14's per-lane operands + exact product/reduction order
//      (absmax signature must return to 2.384186e-07).
// Flags: per-wave counters Pw[16]; combined-issue polls; acquire-cached sound.
__global__ __launch_bounds__(1024)
__attribute__((amdgpu_waves_per_eu(4, 4)))
void lstm_phase(
    const float* __restrict__ x,
    const float* __restrict__ Wx0, const float* __restrict__ U0, const float* __restrict__ b0,
    const float* __restrict__ Wx1, const float* __restrict__ U1, const float* __restrict__ b1,
    const float* __restrict__ Wx2, const float* __restrict__ U2, const float* __restrict__ b2,
    const float* __restrict__ Wx3, const float* __restrict__ U3, const float* __restrict__ b3,
    const float* __restrict__ Wd,  const float* __restrict__ bd,
    float* __restrict__ out)
{
    // dwords: hbuf f16 [0,18432) | xs [18432,27136) | red [27136,27200) |
    //         bs [27200,28224) | Pw [28224,28240)
    extern __shared__ uint32_t smem[];
    __fp16* hb16 = (__fp16*)smem;              // [l][slot8][row 16][unit 64 pad 72]
    float*  xs   = (float*)(smem + 18432);     // [t][17]; reused as hK stage in epilogue
    float*  red  = (float*)(smem + 27136);     // [2][16] epilogue partials (R14 layout)
    float*  bs   = (float*)(smem + 27200);     // [l][256] pre-scaled bias
    int*    Pw   = (int*)(smem + 28224);       // [4l+w] per-wave progress

    const int tid  = threadIdx.x;
    const int lane = tid & 63;
    const int l15  = lane & 15;
    const int quad = lane >> 4;
    const int wv   = tid >> 6;
    const int l    = wv >> 2;                  // layer
    const int w    = wv & 3;                   // unit-quarter
    const int b0i  = blockIdx.x * 16;

    // ---- staging: zero hbuf + flags, stage x, pre-scaled bias table ----
    for (int i = tid; i < 28240; i += 1024) smem[i] = 0;
    __syncthreads();
    for (int i = tid; i < 16 * TT; i += 1024) {
        int row = i >> 9, t_ = i & (TT - 1);
        xs[t_ * 17 + row] = x[(b0i + row) * TT + t_];
    }
    {
        int l_ = tid >> 8, c_ = tid & 255;
        const float* bsrc = (l_ == 0) ? b0 : (l_ == 1) ? b1 : (l_ == 2) ? b2 : b3;
        float sc_ = ((c_ >> 6) == 2) ? 1.0f : -1.4426950408889634f;
        bs[tid] = bsrc[c_] * sc_;
    }

    const float* Uw   = (l == 0) ? U0 : (l == 1) ? U1 : (l == 2) ? U2 : U3;
    const float* Wsrc = (l == 1) ? Wx1 : (l == 2) ? Wx2 : (l == 3) ? Wx3 : U0;

    REP4(DECLT)
    REP4(LOADT)

    f32x4 acc0, acc1, acc2, acc3;
    f32x4 cst0 = {0,0,0,0};
    f32x4 hK0  = {0,0,0,0};

    __fp16* hb_l  = hb16 + l * 9216;           // own layer buffer (8 slots x 1152 f16)
    const __fp16* hb_in = hb16 + (l > 0 ? (l - 1) * 9216 : 0);
    const float*  bsl   = bs + l * 256 + 16 * w + 4 * quad;

    f16x8 xBp0 = {}, xBp1 = {};
    float xvp = 0.f;

    __syncthreads();

    if (l == 0) xvp = xs[l15];                 // layer-0 operand for t=0

    // cached counters: 3 partners, 4 producers, 4 consumers
    int pS0 = 0, pS1 = 0, pS2 = 0;
    int pI0 = 0, pI1 = 0, pI2 = 0, pI3 = 0;
    int pO0 = 0, pO1 = 0, pO2 = 0, pO3 = 0;
    const int k0 = 4*l + ((w + 1) & 3), k1 = 4*l + ((w + 2) & 3), k2 = 4*l + ((w + 3) & 3);

    for (int t = 0; t < TT; ++t) {
        // ---- input wait (layer l-1, all 4 producers >= t+1) + xBp read ----
        if (l > 0) {
            if (pI0 <= t || pI1 <= t || pI2 <= t || pI3 <= t) {
                do {
                    pI0 = PLOAD(4*l - 4); pI1 = PLOAD(4*l - 3);
                    pI2 = PLOAD(4*l - 2); pI3 = PLOAD(4*l - 1);
                } while (pI0 <= t || pI1 <= t || pI2 <= t || pI3 <= t);
            }
            const __fp16* xp_ = hb_in + (t & 7) * 1152 + l15 * 72 + 8 * quad;
            xBp0 = *(const f16x8*)xp_;
            xBp1 = *(const f16x8*)(xp_ + 32);
        }
        // ---- partner wait (3 partners >= t) ----
        if (t > 0 && (pS0 < t || pS1 < t || pS2 < t)) {
            do {
                pS0 = PLOAD(k0); pS1 = PLOAD(k1); pS2 = PLOAD(k2);
            } while (pS0 < t || pS1 < t || pS2 < t);
        }
        // ---- ring-reuse guard (4 consumers >= t-7; slot t&7 = h(t-8)) ----
        if (l < 3 && t >= 8) {
            const int need = t - 7;
            if (pO0 < need || pO1 < need || pO2 < need || pO3 < need) {
                do {
                    pO0 = PLOAD(4*l + 4); pO1 = PLOAD(4*l + 5);
                    pO2 = PLOAD(4*l + 6); pO3 = PLOAD(4*l + 7);
                } while (pO0 < need || pO1 < need || pO2 < need || pO3 < need);
            }
        }
        __builtin_amdgcn_s_setprio(1);
        MFMA_SEG(t)
        __builtin_amdgcn_s_setprio(0);
        {
            const bool sv_ = (l == 3) && (t == TT - 1);
            GATE_SEG(t, sv_)
        }
        // wave-idempotent publish (NOT fetch_add: per-lane atomics add 64/step!)
        __hip_atomic_store(&Pw[wv], t + 1, __ATOMIC_RELEASE, __HIP_MEMORY_SCOPE_WORKGROUP);
        if (l == 0 && t + 1 < TT) xvp = xs[(t + 1) * 17 + l15];
    }

    __syncthreads();

    // ---- epilogue, BIT-EXACT R14 arithmetic ----
    // Stage 1: layer-3 waves dump f32 hK0 frags (units 16w+4quad+r, row l15).
    if (l == 3) {
        float* hsv = (float*)(smem + 18432);   // xs dead; 4 waves x 256 dwords
        *(f32x4*)(hsv + (w * 64 + lane) * 4) = hK0;
    }
    __syncthreads();
    // Stage 2: waves (3, h=0/1) reassemble R14's per-lane hK0/hK1 and replicate
    // its exact product order + shfl tree + red layout.
    if (l == 3 && w < 2) {
        const int h = w;
        const float* hsv = (const float*)(smem + 18432);
        f32x4 hk0 = *(const f32x4*)(hsv + ((2 * h)     * 64 + lane) * 4);
        f32x4 hk1 = *(const f32x4*)(hsv + ((2 * h + 1) * 64 + lane) * 4);
        float p = 0.f;
        #pragma unroll
        for (int r = 0; r < 4; ++r) {
            p += hk0[r] * Wd[32 * h + 4 * quad + r];
            p += hk1[r] * Wd[32 * h + 16 + 4 * quad + r];
        }
        p += __shfl_down(p, 32, 64);
        p += __shfl_down(p, 16, 64);
        if (lane < 16) red[h * 16 + lane] = p;
    }
    __syncthreads();
    if (wv == 0 && lane < 16)
        out[b0i + lane] = red[lane] + red[16 + lane] + bd[0];
}

extern "C" void kernel_launch(void* const* d_in, const int* in_sizes, int n_in,
                              void* d_out, int out_size, void* d_ws, size_t ws_size,
                              hipStream_t stream) {
    const float* x   = (const float*)d_in[0];
    const float* Wx0 = (const float*)d_in[1];
    const float* U0  = (const float*)d_in[2];
    const float* b0  = (const float*)d_in[3];
    const float* Wx1 = (const float*)d_in[4];
    const float* U1  = (const float*)d_in[5];
    const float* b1  = (const float*)d_in[6];
    const float* Wx2 = (const float*)d_in[7];
    const float* U2  = (const float*)d_in[8];
    const float* b2  = (const float*)d_in[9];
    const float* Wx3 = (const float*)d_in[10];
    const float* U3  = (const float*)d_in[11];
    const float* b3  = (const float*)d_in[12];
    const float* Wd  = (const float*)d_in[13];
    const float* bd  = (const float*)d_in[14];
    float* out = (float*)d_out;

    static const int kLds = 28240 * 4;   // 112960 B dynamic LDS
    (void)hipFuncSetAttribute((const void*)lstm_phase,
                              hipFuncAttributeMaxDynamicSharedMemorySize, kLds);
    hipLaunchKernelGGL(lstm_phase, dim3(64), dim3(1024), kLds, stream,
                       x, Wx0, U0, b0, Wx1, U1, b1, Wx2, U2, b2, Wx3, U3, b3,
                       Wd, bd, out);
}

// Round 13
// 1093.126 us; speedup vs baseline: 1.0014x; 1.0014x over previous
//
#include <hip/hip_runtime.h>
#include <stdint.h>

#define TT 512

typedef __fp16   f16x8  __attribute__((ext_vector_type(8)));
typedef float    f32x4  __attribute__((ext_vector_type(4)));
typedef __fp16   fp16x2 __attribute__((ext_vector_type(2)));
typedef uint32_t u32x2  __attribute__((ext_vector_type(2)));

__device__ __forceinline__ f32x4 mfma16(f16x8 a, f16x8 b, f32x4 c) {
    return __builtin_amdgcn_mfma_f32_16x16x32_f16(a, b, c, 0, 0, 0);
}
__device__ __forceinline__ uint32_t pkf16(float a, float b) {
    fp16x2 h = __builtin_amdgcn_cvt_pkrtz(a, b);
    return __builtin_bit_cast(uint32_t, h);
}

#define REP4(M) M(0)M(1)M(2)M(3)

// A-operand gather with per-column scale SC (weights transposed, z^T form):
// A[m=16T+l15][k=32F+8q+j] = SRC[k][16T+l15] * SC
#define GA(SRC, T, F, SC) (f16x8){ \
  (__fp16)((SRC)[(32*(F)+8*quad+0)*256 + 16*(T)+l15] * (SC)), \
  (__fp16)((SRC)[(32*(F)+8*quad+1)*256 + 16*(T)+l15] * (SC)), \
  (__fp16)((SRC)[(32*(F)+8*quad+2)*256 + 16*(T)+l15] * (SC)), \
  (__fp16)((SRC)[(32*(F)+8*quad+3)*256 + 16*(T)+l15] * (SC)), \
  (__fp16)((SRC)[(32*(F)+8*quad+4)*256 + 16*(T)+l15] * (SC)), \
  (__fp16)((SRC)[(32*(F)+8*quad+5)*256 + 16*(T)+l15] * (SC)), \
  (__fp16)((SRC)[(32*(F)+8*quad+6)*256 + 16*(T)+l15] * (SC)), \
  (__fp16)((SRC)[(32*(F)+8*quad+7)*256 + 16*(T)+l15] * (SC)) }

// Wave (l,w) owns tiles Tg = 4*j + w (j = gate: 0:i 1:f 2:g 3:o), i.e.
// z-cols 64j+16w..+15 -> units 16w..16w+15, all 4 gates. 8 W + 8 U MFMA/step.
// i/f/o columns pre-scaled by -log2e (R19 fold); bias pre-scaled in LDS table.
#define DECLT(j) f16x8 uA##j##_0, uA##j##_1, wA##j##_0, wA##j##_1;
#define LOADT(j) { \
  const int Tg_ = 4*(j) + w; \
  const float sc_ = ((j) == 2) ? 1.0f : -1.4426950408889634f; \
  uA##j##_0 = GA(Uw, Tg_, 0, sc_); uA##j##_1 = GA(Uw, Tg_, 1, sc_); \
  if (l > 0) { wA##j##_0 = GA(Wsrc, Tg_, 0, sc_); wA##j##_1 = GA(Wsrc, Tg_, 1, sc_); } \
  else { wA##j##_0 = __builtin_bit_cast(f16x8, (f32x4){ \
           Wx0[16*Tg_+4*quad+0] * sc_, Wx0[16*Tg_+4*quad+1] * sc_, \
           Wx0[16*Tg_+4*quad+2] * sc_, Wx0[16*Tg_+4*quad+3] * sc_ }); \
         wA##j##_1 = wA##j##_0; } }

#define MW0(j) acc##j = mfma16(wA##j##_0, xBp0, bias##j);
#define MW1(j) acc##j = mfma16(wA##j##_1, xBp1, acc##j);
#define MX(j)  acc##j = bias##j + __builtin_bit_cast(f32x4, wA##j##_0) * xvp4;
#define MU0(j) acc##j = mfma16(uA##j##_0, hB0, acc##j);
#define MU1(j) acc##j = mfma16(uA##j##_1, hB1, acc##j);

// MFMA segment (R14 proven order): bias + hB ds_reads at top, latency hides
// under the partner-independent W burst; U burst last.
#define MFMA_SEG(t_) { \
  f32x4 bias0 = *(const f32x4*)(bsl +   0); \
  f32x4 bias1 = *(const f32x4*)(bsl +  64); \
  f32x4 bias2 = *(const f32x4*)(bsl + 128); \
  f32x4 bias3 = *(const f32x4*)(bsl + 192); \
  const __fp16* hp_ = hb_l + (((t_)-1)&7)*1152 + l15*72 + 8*quad; \
  f16x8 hB0 = *(const f16x8*)hp_; \
  f16x8 hB1 = *(const f16x8*)(hp_ + 32); \
  if (l > 0) { REP4(MW0) REP4(MW1) } \
  else       { f32x4 xvp4 = {xvp, xvp, xvp, xvp}; REP4(MX) } \
  REP4(MU0) \
  REP4(MU1) }

// Gates: z' for i/f/o pre-scaled -> exp2 direct; g unscaled (relu only).
#define GATE_SEG(tg_, SV_) { \
  f32x4 ei_, ef_, eo_; \
  _Pragma("unroll") for (int r_ = 0; r_ < 4; ++r_) { \
    ei_[r_] = __builtin_amdgcn_exp2f(acc0[r_]); \
    ef_[r_] = __builtin_amdgcn_exp2f(acc1[r_]); \
    eo_[r_] = __builtin_amdgcn_exp2f(acc3[r_]); \
  } \
  f32x4 si_, sf_, so_; \
  _Pragma("unroll") for (int r_ = 0; r_ < 4; ++r_) { \
    si_[r_] = __builtin_amdgcn_rcpf(1.0f + ei_[r_]); \
    sf_[r_] = __builtin_amdgcn_rcpf(1.0f + ef_[r_]); \
    so_[r_] = __builtin_amdgcn_rcpf(1.0f + eo_[r_]); \
  } \
  const f32x4 z4_ = {0.f, 0.f, 0.f, 0.f}; \
  f32x4 rg_ = __builtin_elementwise_max(acc2, z4_); \
  f32x4 cv_ = sf_ * cst0 + si_ * rg_; \
  cst0 = cv_; \
  f32x4 hv_ = so_ * __builtin_elementwise_max(cv_, z4_); \
  u32x2 pv_ = { pkf16(hv_[0], hv_[1]), pkf16(hv_[2], hv_[3]) }; \
  __fp16* hw_ = hb_l + ((tg_)&7)*1152 + l15*72 + 16*w + 4*quad; \
  *(u32x2*)hw_ = pv_; \
  if (SV_) hK0 = hv_; }

#define PLOAD(idx) __hip_atomic_load(&Pw[idx], __ATOMIC_ACQUIRE, __HIP_MEMORY_SCOPE_WORKGROUP)

// 64 blocks x 1024 threads; block = 16 batch rows; 16 waves = 4 layers x 4
// unit-quarters; 4 waves/SIMD (TLP test, take 3). R22's result was VOID too:
// amdgpu_waves_per_eu(4,4) capped allocation at 64 VGPR -> weight arrays
// spilled to scratch (WRITE_SIZE 3460->9220 KB, FETCH +2.2MB) -> 2x slowdown.
// R23 drops the attribute: 1-block/CU residency (113KB LDS) already guarantees
// 16 waves/CU = 4 waves/SIMD for any VGPR <= 512; let the allocator breathe.
// Flag publish: wave-idempotent atomic_store (R22 fix, absmax-verified).
// Epilogue: bit-exact R14 reconstruction (R22, absmax 2.384186e-07 verified).
__global__ __launch_bounds__(1024)
void lstm_phase(
    const float* __restrict__ x,
    const float* __restrict__ Wx0, const float* __restrict__ U0, const float* __restrict__ b0,
    const float* __restrict__ Wx1, const float* __restrict__ U1, const float* __restrict__ b1,
    const float* __restrict__ Wx2, const float* __restrict__ U2, const float* __restrict__ b2,
    const float* __restrict__ Wx3, const float* __restrict__ U3, const float* __restrict__ b3,
    const float* __restrict__ Wd,  const float* __restrict__ bd,
    float* __restrict__ out)
{
    // dwords: hbuf f16 [0,18432) | xs [18432,27136) | red [27136,27200) |
    //         bs [27200,28224) | Pw [28224,28240)
    extern __shared__ uint32_t smem[];
    __fp16* hb16 = (__fp16*)smem;              // [l][slot8][row 16][unit 64 pad 72]
    float*  xs   = (float*)(smem + 18432);     // [t][17]; reused as hK stage in epilogue
    float*  red  = (float*)(smem + 27136);     // [2][16] epilogue partials (R14 layout)
    float*  bs   = (float*)(smem + 27200);     // [l][256] pre-scaled bias
    int*    Pw   = (int*)(smem + 28224);       // [4l+w] per-wave progress

    const int tid  = threadIdx.x;
    const int lane = tid & 63;
    const int l15  = lane & 15;
    const int quad = lane >> 4;
    const int wv   = tid >> 6;
    const int l    = wv >> 2;                  // layer
    const int w    = wv & 3;                   // unit-quarter
    const int b0i  = blockIdx.x * 16;

    // ---- staging: zero hbuf + flags, stage x, pre-scaled bias table ----
    for (int i = tid; i < 28240; i += 1024) smem[i] = 0;
    __syncthreads();
    for (int i = tid; i < 16 * TT; i += 1024) {
        int row = i >> 9, t_ = i & (TT - 1);
        xs[t_ * 17 + row] = x[(b0i + row) * TT + t_];
    }
    {
        int l_ = tid >> 8, c_ = tid & 255;
        const float* bsrc = (l_ == 0) ? b0 : (l_ == 1) ? b1 : (l_ == 2) ? b2 : b3;
        float sc_ = ((c_ >> 6) == 2) ? 1.0f : -1.4426950408889634f;
        bs[tid] = bsrc[c_] * sc_;
    }

    const float* Uw   = (l == 0) ? U0 : (l == 1) ? U1 : (l == 2) ? U2 : U3;
    const float* Wsrc = (l == 1) ? Wx1 : (l == 2) ? Wx2 : (l == 3) ? Wx3 : U0;

    REP4(DECLT)
    REP4(LOADT)

    f32x4 acc0, acc1, acc2, acc3;
    f32x4 cst0 = {0,0,0,0};
    f32x4 hK0  = {0,0,0,0};

    __fp16* hb_l  = hb16 + l * 9216;           // own layer buffer (8 slots x 1152 f16)
    const __fp16* hb_in = hb16 + (l > 0 ? (l - 1) * 9216 : 0);
    const float*  bsl   = bs + l * 256 + 16 * w + 4 * quad;

    f16x8 xBp0 = {}, xBp1 = {};
    float xvp = 0.f;

    __syncthreads();

    if (l == 0) xvp = xs[l15];                 // layer-0 operand for t=0

    // cached counters: 3 partners, 4 producers, 4 consumers
    int pS0 = 0, pS1 = 0, pS2 = 0;
    int pI0 = 0, pI1 = 0, pI2 = 0, pI3 = 0;
    int pO0 = 0, pO1 = 0, pO2 = 0, pO3 = 0;
    const int k0 = 4*l + ((w + 1) & 3), k1 = 4*l + ((w + 2) & 3), k2 = 4*l + ((w + 3) & 3);

    for (int t = 0; t < TT; ++t) {
        // ---- input wait (layer l-1, all 4 producers >= t+1) + xBp read ----
        if (l > 0) {
            if (pI0 <= t || pI1 <= t || pI2 <= t || pI3 <= t) {
                do {
                    pI0 = PLOAD(4*l - 4); pI1 = PLOAD(4*l - 3);
                    pI2 = PLOAD(4*l - 2); pI3 = PLOAD(4*l - 1);
                } while (pI0 <= t || pI1 <= t || pI2 <= t || pI3 <= t);
            }
            const __fp16* xp_ = hb_in + (t & 7) * 1152 + l15 * 72 + 8 * quad;
            xBp0 = *(const f16x8*)xp_;
            xBp1 = *(const f16x8*)(xp_ + 32);
        }
        // ---- partner wait (3 partners >= t) ----
        if (t > 0 && (pS0 < t || pS1 < t || pS2 < t)) {
            do {
                pS0 = PLOAD(k0); pS1 = PLOAD(k1); pS2 = PLOAD(k2);
            } while (pS0 < t || pS1 < t || pS2 < t);
        }
        // ---- ring-reuse guard (4 consumers >= t-7; slot t&7 = h(t-8)) ----
        if (l < 3 && t >= 8) {
            const int need = t - 7;
            if (pO0 < need || pO1 < need || pO2 < need || pO3 < need) {
                do {
                    pO0 = PLOAD(4*l + 4); pO1 = PLOAD(4*l + 5);
                    pO2 = PLOAD(4*l + 6); pO3 = PLOAD(4*l + 7);
                } while (pO0 < need || pO1 < need || pO2 < need || pO3 < need);
            }
        }
        __builtin_amdgcn_s_setprio(1);
        MFMA_SEG(t)
        __builtin_amdgcn_s_setprio(0);
        {
            const bool sv_ = (l == 3) && (t == TT - 1);
            GATE_SEG(t, sv_)
        }
        // wave-idempotent publish (NOT fetch_add: per-lane atomics add 64/step!)
        __hip_atomic_store(&Pw[wv], t + 1, __ATOMIC_RELEASE, __HIP_MEMORY_SCOPE_WORKGROUP);
        if (l == 0 && t + 1 < TT) xvp = xs[(t + 1) * 17 + l15];
    }

    __syncthreads();

    // ---- epilogue, BIT-EXACT R14 arithmetic ----
    // Stage 1: layer-3 waves dump f32 hK0 frags (units 16w+4quad+r, row l15).
    if (l == 3) {
        float* hsv = (float*)(smem + 18432);   // xs dead; 4 waves x 256 dwords
        *(f32x4*)(hsv + (w * 64 + lane) * 4) = hK0;
    }
    __syncthreads();
    // Stage 2: waves (3, h=0/1) reassemble R14's per-lane hK0/hK1 and replicate
    // its exact product order + shfl tree + red layout.
    if (l == 3 && w < 2) {
        const int h = w;
        const float* hsv = (const float*)(smem + 18432);
        f32x4 hk0 = *(const f32x4*)(hsv + ((2 * h)     * 64 + lane) * 4);
        f32x4 hk1 = *(const f32x4*)(hsv + ((2 * h + 1) * 64 + lane) * 4);
        float p = 0.f;
        #pragma unroll
        for (int r = 0; r < 4; ++r) {
            p += hk0[r] * Wd[32 * h + 4 * quad + r];
            p += hk1[r] * Wd[32 * h + 16 + 4 * quad + r];
        }
        p += __shfl_down(p, 32, 64);
        p += __shfl_down(p, 16, 64);
        if (lane < 16) red[h * 16 + lane] = p;
    }
    __syncthreads();
    if (wv == 0 && lane < 16)
        out[b0i + lane] = red[lane] + red[16 + lane] + bd[0];
}

extern "C" void kernel_launch(void* const* d_in, const int* in_sizes, int n_in,
                              void* d_out, int out_size, void* d_ws, size_t ws_size,
                              hipStream_t stream) {
    const float* x   = (const float*)d_in[0];
    const float* Wx0 = (const float*)d_in[1];
    const float* U0  = (const float*)d_in[2];
    const float* b0  = (const float*)d_in[3];
    const float* Wx1 = (const float*)d_in[4];
    const float* U1  = (const float*)d_in[5];
    const float* b1  = (const float*)d_in[6];
    const float* Wx2 = (const float*)d_in[7];
    const float* U2  = (const float*)d_in[8];
    const float* b2  = (const float*)d_in[9];
    const float* Wx3 = (const float*)d_in[10];
    const float* U3  = (const float*)d_in[11];
    const float* b3  = (const float*)d_in[12];
    const float* Wd  = (const float*)d_in[13];
    const float* bd  = (const float*)d_in[14];
    float* out = (float*)d_out;

    static const int kLds = 28240 * 4;   // 112960 B dynamic LDS
    (void)hipFuncSetAttribute((const void*)lstm_phase,
                              hipFuncAttributeMaxDynamicSharedMemorySize, kLds);
    hipLaunchKernelGGL(lstm_phase, dim3(64), dim3(1024), kLds, stream,
                       x, Wx0, U0, b0, Wx1, U1, b1, Wx2, U2, b2, Wx3, U3, b3,
                       Wd, bd, out);
}

// Round 14
// 651.713 us; speedup vs baseline: 1.6796x; 1.6773x over previous
//
#include <hip/hip_runtime.h>
#include <stdint.h>

#define TT 512

typedef __fp16   f16x8  __attribute__((ext_vector_type(8)));
typedef float    f32x4  __attribute__((ext_vector_type(4)));
typedef __fp16   fp16x2 __attribute__((ext_vector_type(2)));
typedef uint32_t u32x2  __attribute__((ext_vector_type(2)));

__device__ __forceinline__ f32x4 mfma16(f16x8 a, f16x8 b, f32x4 c) {
    return __builtin_amdgcn_mfma_f32_16x16x32_f16(a, b, c, 0, 0, 0);
}
__device__ __forceinline__ uint32_t pkf16(float a, float b) {
    fp16x2 h = __builtin_amdgcn_cvt_pkrtz(a, b);
    return __builtin_bit_cast(uint32_t, h);
}

#define REP8(M) M(0)M(1)M(2)M(3)M(4)M(5)M(6)M(7)

// A-operand gather with per-column scale SC (weights transposed, z^T form):
// A[m=16T+l15][k=32F+8q+j] = SRC[k][16T+l15] * SC
#define GA(SRC, T, F, SC) (f16x8){ \
  (__fp16)((SRC)[(32*(F)+8*quad+0)*256 + 16*(T)+l15] * (SC)), \
  (__fp16)((SRC)[(32*(F)+8*quad+1)*256 + 16*(T)+l15] * (SC)), \
  (__fp16)((SRC)[(32*(F)+8*quad+2)*256 + 16*(T)+l15] * (SC)), \
  (__fp16)((SRC)[(32*(F)+8*quad+3)*256 + 16*(T)+l15] * (SC)), \
  (__fp16)((SRC)[(32*(F)+8*quad+4)*256 + 16*(T)+l15] * (SC)), \
  (__fp16)((SRC)[(32*(F)+8*quad+5)*256 + 16*(T)+l15] * (SC)), \
  (__fp16)((SRC)[(32*(F)+8*quad+6)*256 + 16*(T)+l15] * (SC)), \
  (__fp16)((SRC)[(32*(F)+8*quad+7)*256 + 16*(T)+l15] * (SC)) }

// Wave (l,h) owns zcols {64g + 32h + 16q' .. +15}: local j = 2g+q' -> tile Tg.
// Gate index = j>>1 (0:i 1:f 2:g 3:o). i/f/o columns+bias pre-scaled by -log2e
// at load time (R19 fold; VALU-neutral but keeps issue pressure low).
#define DECLT(j) f16x8 uA##j##_0, uA##j##_1, wA##j##_0, wA##j##_1; f32x4 bias##j;
#define LOADT(j) { \
  const int Tg_ = ((j)>>1)*4 + 2*h + ((j)&1); \
  const float sc_ = (((j)>>1) == 2) ? 1.0f : -1.4426950408889634f; \
  uA##j##_0 = GA(Uw, Tg_, 0, sc_); uA##j##_1 = GA(Uw, Tg_, 1, sc_); \
  bias##j = (f32x4){ bw_[16*Tg_ + 4*quad + 0] * sc_, bw_[16*Tg_ + 4*quad + 1] * sc_, \
                     bw_[16*Tg_ + 4*quad + 2] * sc_, bw_[16*Tg_ + 4*quad + 3] * sc_ }; \
  if (l > 0) { wA##j##_0 = GA(Wsrc, Tg_, 0, sc_); wA##j##_1 = GA(Wsrc, Tg_, 1, sc_); } \
  else { wA##j##_0 = __builtin_bit_cast(f16x8, (f32x4){ \
           Wx0[16*Tg_+4*quad+0] * sc_, Wx0[16*Tg_+4*quad+1] * sc_, \
           Wx0[16*Tg_+4*quad+2] * sc_, Wx0[16*Tg_+4*quad+3] * sc_ }); \
         wA##j##_1 = wA##j##_0; } }

// MFMA segment: hB ds_read hoisted at top (latency hides under the 16
// partner-independent W-MFMAs that follow) -- R14's proven order, untouched.
#define MW0(j) acc##j = mfma16(wA##j##_0, xBp0, bias##j);
#define MW1(j) acc##j = mfma16(wA##j##_1, xBp1, acc##j);
#define MX(j)  acc##j = bias##j + __builtin_bit_cast(f32x4, wA##j##_0) * xvp4;
#define MU0(j) acc##j = mfma16(uA##j##_0, hB0, acc##j);
#define MU1(j) acc##j = mfma16(uA##j##_1, hB1, acc##j);

#define MFMA_SEG(t_) { \
  const __fp16* hp_ = hb_l + (((t_)-1)&7)*1152 + l15*72 + 8*quad; \
  f16x8 hB0 = *(const f16x8*)hp_; \
  f16x8 hB1 = *(const f16x8*)(hp_ + 32); \
  if (l > 0) { REP8(MW0) REP8(MW1) } \
  else       { f32x4 xvp4 = {xvp, xvp, xvp, xvp}; REP8(MX) } \
  REP8(MU0) \
  REP8(MU1) }

// Gates: z' for i/f/o pre-scaled -> exp2 direct; g unscaled (relu only).
#define GATES(qp, Ai, Af, Ag, Ao, CST, SAVEK, HK) { \
  f32x4 ei_, ef_, eo_; \
  _Pragma("unroll") for (int r_ = 0; r_ < 4; ++r_) { \
    ei_[r_] = __builtin_amdgcn_exp2f(Ai[r_]); \
    ef_[r_] = __builtin_amdgcn_exp2f(Af[r_]); \
    eo_[r_] = __builtin_amdgcn_exp2f(Ao[r_]); \
  } \
  f32x4 si_, sf_, so_; \
  _Pragma("unroll") for (int r_ = 0; r_ < 4; ++r_) { \
    si_[r_] = __builtin_amdgcn_rcpf(1.0f + ei_[r_]); \
    sf_[r_] = __builtin_amdgcn_rcpf(1.0f + ef_[r_]); \
    so_[r_] = __builtin_amdgcn_rcpf(1.0f + eo_[r_]); \
  } \
  const f32x4 z4_ = {0.f, 0.f, 0.f, 0.f}; \
  f32x4 rg_ = __builtin_elementwise_max(Ag, z4_); \
  f32x4 cv_ = sf_ * CST + si_ * rg_; \
  CST = cv_; \
  f32x4 hv_ = so_ * __builtin_elementwise_max(cv_, z4_); \
  u32x2 pv_ = { pkf16(hv_[0], hv_[1]), pkf16(hv_[2], hv_[3]) }; \
  *(u32x2*)(hw_ + 16*(qp)) = pv_; \
  if (SAVEK) HK = hv_; }

#define GATE_SEG(tg_, SV_) { \
  __fp16* hw_ = hb_l + ((tg_)&7)*1152 + l15*72 + 32*h + 4*quad; \
  GATES(0, acc0, acc2, acc4, acc6, cst0, SV_, hK0) \
  GATES(1, acc1, acc3, acc5, acc7, cst1, SV_, hK1) }

// Spin-wait with s_sleep: the wave PARKS (~64cy) instead of burning the SIMD's
// issue port with ds_read+cmp+branch spins. R20 counters: VALUBusy 63% of
// active cycles (~1700cy/SIMD/step) vs ~600cy of real gate work -> ~1100cy of
// spin issue stealing slots from the co-resident wave's real work.
#define WAITGE(cache, idx, need) \
  while ((cache) < (need)) { \
    __builtin_amdgcn_s_sleep(1); \
    (cache) = __hip_atomic_load(&Pf[idx], __ATOMIC_ACQUIRE, __HIP_MEMORY_SCOPE_WORKGROUP); \
  }

// 64 blocks x 512 threads; block = 16 batch rows; 8 waves = 4 layers x 2 unit-halves.
// R24 = byte-exact R20 (best, 585us steady: async flags + exp2 fold + setprio)
// + s_sleep(1) in WAITGE ONLY.
// R21-R23 lesson: 4 waves/SIMD is register-infeasible (1024-thr block caps the
// budget at ~64 arch VGPR -> weight spills; R13's fitting variant was slower).
// 2 waves/SIMD + issue-silent waits is the remaining lever against the ~1100
// cyc/step of spin-issue contention.
__global__ __launch_bounds__(512)
__attribute__((amdgpu_waves_per_eu(2, 2)))
void lstm_phase(
    const float* __restrict__ x,
    const float* __restrict__ Wx0, const float* __restrict__ U0, const float* __restrict__ b0,
    const float* __restrict__ Wx1, const float* __restrict__ U1, const float* __restrict__ b1,
    const float* __restrict__ Wx2, const float* __restrict__ U2, const float* __restrict__ b2,
    const float* __restrict__ Wx3, const float* __restrict__ U3, const float* __restrict__ b3,
    const float* __restrict__ Wd,  const float* __restrict__ bd,
    float* __restrict__ out)
{
    // dwords: hbuf f16 [0,18432) | x_s f32 [18432,27136) | red [27136,27168) | P [27168,27176)
    extern __shared__ uint32_t smem[];
    __fp16* hb16 = (__fp16*)smem;              // [l][slot8][row 16][unit 64 pad 72]
    float*  xs   = (float*)(smem + 18432);     // [t][17]
    float*  red  = (float*)(smem + 27136);     // [2][16] epilogue partials
    int*    Pf   = (int*)(smem + 27168);       // [8] per-wave progress counters

    const int tid  = threadIdx.x;
    const int lane = tid & 63;
    const int l15  = lane & 15;
    const int quad = lane >> 4;
    const int wv   = tid >> 6;
    const int l    = wv >> 1;                  // layer
    const int h    = wv & 1;                   // unit-half
    const int b0i  = blockIdx.x * 16;

    // ---- staging: zero hbuf + flags, stage x ----
    for (int i = tid; i < 27176; i += 512) smem[i] = 0;
    __syncthreads();
    for (int i = tid; i < 16 * TT; i += 512) {
        int row = i >> 9, t_ = i & (TT - 1);
        xs[t_ * 17 + row] = x[(b0i + row) * TT + t_];
    }

    const float* Uw   = (l == 0) ? U0 : (l == 1) ? U1 : (l == 2) ? U2 : U3;
    const float* bw_  = (l == 0) ? b0 : (l == 1) ? b1 : (l == 2) ? b2 : b3;
    const float* Wsrc = (l == 1) ? Wx1 : (l == 2) ? Wx2 : (l == 3) ? Wx3 : U0;

    REP8(DECLT)
    REP8(LOADT)

    f32x4 acc0, acc1, acc2, acc3, acc4, acc5, acc6, acc7;
    f32x4 cst0 = {0,0,0,0}, cst1 = {0,0,0,0};
    f32x4 hK0  = {0,0,0,0}, hK1  = {0,0,0,0};

    __fp16* hb_l  = hb16 + l * 9216;           // own buffer (8 slots x 1152 f16)
    const __fp16* hb_in = hb16 + (l > 0 ? (l - 1) * 9216 : 0);

    f16x8 xBp0 = {}, xBp1 = {};
    float xvp = 0.f;

    __syncthreads();

    if (l == 0) xvp = xs[l15];                 // layer-0 operand for t=0

    int pA0 = 0, pA1 = 0, pP = 0, pC0 = 0, pC1 = 0;   // cached counter values

    for (int t = 0; t < TT; ++t) {
        if (l > 0) {
            WAITGE(pA0, 2*l - 2, t + 1)
            WAITGE(pA1, 2*l - 1, t + 1)
            const __fp16* xp_ = hb_in + (t & 7) * 1152 + l15 * 72 + 8 * quad;
            xBp0 = *(const f16x8*)xp_;
            xBp1 = *(const f16x8*)(xp_ + 32);
        }
        if (t > 0) WAITGE(pP, 2*l + 1 - h, t)
        if (l < 3 && t >= 8) {                 // ring-reuse guard (slot t&7 = h(t-8))
            WAITGE(pC0, 2*l + 2, t - 7)
            WAITGE(pC1, 2*l + 3, t - 7)
        }
        __builtin_amdgcn_s_setprio(1);
        MFMA_SEG(t)
        __builtin_amdgcn_s_setprio(0);
        {
            const bool sv_ = (l == 3) && (t == TT - 1);
            GATE_SEG(t, sv_)
        }
        __hip_atomic_store(&Pf[2*l + h], t + 1, __ATOMIC_RELEASE, __HIP_MEMORY_SCOPE_WORKGROUP);
        if (l == 0 && t + 1 < TT) xvp = xs[(t + 1) * 17 + l15];
    }

    __syncthreads();

    // dense epilogue: waves (3,h); lane holds h[511] f32 for units 32h+16q'+4quad+r, row l15
    if (l == 3) {
        float p = 0.f;
        #pragma unroll
        for (int r = 0; r < 4; ++r) {
            p += hK0[r] * Wd[32 * h + 4 * quad + r];
            p += hK1[r] * Wd[32 * h + 16 + 4 * quad + r];
        }
        p += __shfl_down(p, 32, 64);
        p += __shfl_down(p, 16, 64);
        if (lane < 16) red[h * 16 + lane] = p;
    }
    __syncthreads();
    if (wv == 6 && lane < 16) out[b0i + lane] = red[lane] + red[16 + lane] + bd[0];
}

extern "C" void kernel_launch(void* const* d_in, const int* in_sizes, int n_in,
                              void* d_out, int out_size, void* d_ws, size_t ws_size,
                              hipStream_t stream) {
    const float* x   = (const float*)d_in[0];
    const float* Wx0 = (const float*)d_in[1];
    const float* U0  = (const float*)d_in[2];
    const float* b0  = (const float*)d_in[3];
    const float* Wx1 = (const float*)d_in[4];
    const float* U1  = (const float*)d_in[5];
    const float* b1  = (const float*)d_in[6];
    const float* Wx2 = (const float*)d_in[7];
    const float* U2  = (const float*)d_in[8];
    const float* b2  = (const float*)d_in[9];
    const float* Wx3 = (const float*)d_in[10];
    const float* U3  = (const float*)d_in[11];
    const float* b3  = (const float*)d_in[12];
    const float* Wd  = (const float*)d_in[13];
    const float* bd  = (const float*)d_in[14];
    float* out = (float*)d_out;

    static const int kLds = 27176 * 4;   // 108704 B dynamic LDS
    (void)hipFuncSetAttribute((const void*)lstm_phase,
                              hipFuncAttributeMaxDynamicSharedMemorySize, kLds);
    hipLaunchKernelGGL(lstm_phase, dim3(64), dim3(512), kLds, stream,
                       x, Wx0, U0, b0, Wx1, U1, b1, Wx2, U2, b2, Wx3, U3, b3,
                       Wd, bd, out);
}